// Round 13
// baseline (1154.843 us; speedup 1.0000x reference)
//
#include <hip/hip_runtime.h>

#define B_    4
#define N_    2048
#define D_    1024
#define L_    4
#define M_    256
#define DH_   64
#define H_    16
#define BH_   64      // B_*H_
#define ROWS_ 8192    // B_*N_
#define WN_   1048576 // D_*D_ = 2^20

typedef __bf16 bf16x8 __attribute__((ext_vector_type(8)));
typedef float  f32x4  __attribute__((ext_vector_type(4)));
typedef unsigned short u16;

__device__ __forceinline__ u16 f2b(float f){
  unsigned u = __float_as_uint(f);
  u += 0x7FFFu + ((u >> 16) & 1u);          // RNE
  return (u16)(u >> 16);
}
__device__ __forceinline__ float b2f(u16 h){ return __uint_as_float(((unsigned)h) << 16); }

// global -> LDS direct, 16B per lane. LDS dest is wave-uniform base + lane*16.
__device__ __forceinline__ void gload16(const u16* g, u16* l){
  __builtin_amdgcn_global_load_lds(
      (const __attribute__((address_space(1))) void*)g,
      (__attribute__((address_space(3))) void*)l, 16, 0, 0);
}

// ---------------- fp32 -> bf16 convert (linear, for proj) ----------------
__global__ __launch_bounds__(256) void wcvt_k(const float* __restrict__ s, u16* __restrict__ d, long n){
  long i = ((long)blockIdx.x*256 + threadIdx.x)*4;
  if (i+3 < n){
    float4 v = *(const float4*)(s+i);
    d[i]=f2b(v.x); d[i+1]=f2b(v.y); d[i+2]=f2b(v.z); d[i+3]=f2b(v.w);
  } else {
    for(long j=i;j<n;j++) d[j]=f2b(s[j]);
  }
}

// ---- strided convert: src[l*WN_+j] -> dbase[l*6*WN_+j] ----
__global__ __launch_bounds__(256) void wcvt2_k(const float* __restrict__ s, u16* __restrict__ dbase, long n){
  long i = ((long)blockIdx.x*256 + threadIdx.x)*4;
  if (i < n){
    float4 v = *(const float4*)(s+i);
    long l = i >> 20, j = i & (WN_-1);
    u16* d = dbase + l*(6l*WN_) + j;
    d[0]=f2b(v.x); d[1]=f2b(v.y); d[2]=f2b(v.z); d[3]=f2b(v.w);
  }
}

// ---------------- diagnostic fill ----------------
__global__ void fillf_k(float* o, long n, float v){
  long i=(long)blockIdx.x*256+threadIdx.x; if(i<n) o[i]=v;
}

// ---------------- LayerNorm: fp32 row -> bf16 row ----------------
__global__ __launch_bounds__(256) void ln_k(const float* __restrict__ x,
    const float* __restrict__ g, const float* __restrict__ bt, u16* __restrict__ h){
  int row = blockIdx.x, t = threadIdx.x;
  const float* xr = x + (long)row*D_;
  float4 v = *(const float4*)(xr + t*4);
  float s  = v.x+v.y+v.z+v.w;
  float ss = v.x*v.x+v.y*v.y+v.z*v.z+v.w*v.w;
  #pragma unroll
  for (int m=1;m<64;m<<=1){ s += __shfl_xor(s,m); ss += __shfl_xor(ss,m); }
  __shared__ float ps[4][2];
  int w=t>>6;
  if ((t&63)==0){ ps[w][0]=s; ps[w][1]=ss; }
  __syncthreads();
  s  = ps[0][0]+ps[1][0]+ps[2][0]+ps[3][0];
  ss = ps[0][1]+ps[1][1]+ps[2][1]+ps[3][1];
  float mean = s*(1.0f/D_);
  float rs = rsqrtf(ss*(1.0f/D_) - mean*mean + 1e-5f);
  int c=t*4;
  u16* hr = h + (long)row*D_;
  hr[c+0]=f2b((v.x-mean)*rs*g[c+0]+bt[c+0]);
  hr[c+1]=f2b((v.y-mean)*rs*g[c+1]+bt[c+1]);
  hr[c+2]=f2b((v.z-mean)*rs*g[c+2]+bt[c+2]);
  hr[c+3]=f2b((v.w-mean)*rs*g[c+3]+bt[c+3]);
}

// ================= FAVOR fused kernels =================
#define STAGE_PS(Ps, P) \
  _Pragma("unroll") \
  for (int i=0;i<8;i++){ \
    int c=threadIdx.x+i*256, row=c>>3, c8=c&7; \
    uint4 dv = *(const uint4*)((P) + row*64 + c8*8); \
    *(uint4*)((char*)(Ps) + (row<<7) + ((c8<<4)^((row&7)<<4))) = dv; \
  }
// staging + in-flight diag: dgL[row] = sum_d x^2 / 16 (8 lanes/row -> 3 shfl)
#define STAGE_XS_DG(Xs, X, b, hh, n0, dgL) \
  _Pragma("unroll") \
  for (int i=0;i<2;i++){ \
    int c=threadIdx.x+i*256, row=c>>3, c8=c&7; \
    uint4 dv = *(const uint4*)((X) + ((long)(b)*N_ + (n0)+row)*D_ + (hh)*DH_ + c8*8); \
    *(uint4*)((char*)(Xs) + (row<<7) + ((c8<<4)^((row&7)<<4))) = dv; \
    const u16* pe=(const u16*)&dv; \
    float sq=0.f; \
    _Pragma("unroll") \
    for (int e=0;e<8;e++){ float xv=b2f(pe[e]); sq += xv*xv; } \
    sq += __shfl_xor(sq,1); sq += __shfl_xor(sq,2); sq += __shfl_xor(sq,4); \
    if ((threadIdx.x&7)==0) (dgL)[row]=sq*0.0625f; \
  }
#define DD_MFMA(acc, Xs, Ps, w, lr, lg) \
  __builtin_amdgcn_s_setprio(1); \
  _Pragma("unroll") \
  for (int ks=0;ks<2;ks++){ \
    bf16x8 aF[4], bF[4]; \
    _Pragma("unroll") \
    for (int mi=0;mi<4;mi++){ \
      int row=mi*16+(lr); \
      aF[mi]=*(const bf16x8*)((const char*)(Xs) + (row<<7) + ((((ks<<2)+(lg))<<4)^((row&7)<<4))); \
    } \
    _Pragma("unroll") \
    for (int ni=0;ni<4;ni++){ \
      int row=(w)*64+ni*16+(lr); \
      bF[ni]=*(const bf16x8*)((const char*)(Ps) + (row<<7) + ((((ks<<2)+(lg))<<4)^((row&7)<<4))); \
    } \
    _Pragma("unroll") \
    for (int mi=0;mi<4;mi++) \
      _Pragma("unroll") \
      for (int ni=0;ni<4;ni++) \
        acc[mi][ni]=__builtin_amdgcn_mfma_f32_16x16x32_bf16(aF[mi],bF[ni],acc[mi][ni],0,0,0); \
  } \
  __builtin_amdgcn_s_setprio(0);

// ---- fused: dd(K)+diag+ONLINE-STAB exp -> kp ; ksum/ctx partials ; vsum ----
// V-transpose inlined. grid (8, CH). Emits PURE-exp partials (eps added exactly
// in ctxred2). Per-slot running max with fp32 rescale; telescoping == ref stab.
// Tr writes packed as ds_write_b64 (r=0..3 contiguous in [col][rw] layout).
__global__ __launch_bounds__(256) void ddctx_k(
    const u16* __restrict__ Kb, const u16* __restrict__ P,
    const u16* __restrict__ Vb,
    float* __restrict__ part, float* __restrict__ kspart,
    float* __restrict__ msl, float* __restrict__ vsl, int zoff)
{
  __shared__ __align__(16) char smem[63760];
  u16* Ps = (u16*)smem;               // [0,32768) per-subtile proj
  u16* Tr = (u16*)smem;               // [0,36864) kp^T overlay (256x72)
  u16* Xs = (u16*)(smem+36864);       // 8KB -> 45056
  u16* Vs = (u16*)(smem+45056);       // [64][72] v^T tile -> 54272
  u16* Tv = (u16*)(smem+54272);       // [64][72] raw V rows -> 63488
  float* dgL = (float*)(smem+63488);  // [64] -> 63744
  float* rm  = (float*)(smem+63744);  // [4]
  int t=threadIdx.x, w=t>>6, lane=t&63, lr=lane&15, lg=lane>>4;
  int zl=blockIdx.y, zg=zl+zoff, slot=blockIdx.x;
  int b=zg>>4, hh=zg&15;
  const float SN = 0.35355339059327373f;

  f32x4 cacc[4][4];
  #pragma unroll
  for (int mi=0;mi<4;mi++)
    #pragma unroll
    for (int ni=0;ni<4;ni++) cacc[mi][ni]=(f32x4){0.f,0.f,0.f,0.f};
  float ksp[4]={0.f,0.f,0.f,0.f};
  float vsacc=0.f;                    // valid on (t&3)==0, d=t>>2
  float mrun=-1e30f;

  for (int s=0;s<4;++s){
    int n0 = slot*256 + s*64;
    STAGE_PS(Ps, P); STAGE_XS_DG(Xs, Kb, b, hh, n0, dgL);
    {   // raw V rows [n][d] into Tv
      int row=t>>2, c16=(t&3)*16;
      const u16* src = Vb + ((long)b*N_ + n0+row)*D_ + hh*DH_ + c16;
      *(uint4*)&Tv[row*72+c16]   = *(const uint4*)src;
      *(uint4*)&Tv[row*72+c16+8] = *(const uint4*)(src+8);
    }
    __syncthreads();
    {   // transpose Tv[n][d] -> Vs[d][n]
      int d=t>>2, nc=(t&3)*16;
      union { u16 u[16]; uint4 q[2]; } tv;
      #pragma unroll
      for (int j=0;j<16;j++) tv.u[j]=Tv[(nc+j)*72+d];
      *(uint4*)&Vs[d*72+nc]   = tv.q[0];
      *(uint4*)&Vs[d*72+nc+8] = tv.q[1];
    }
    f32x4 acc[4][4];
    #pragma unroll
    for (int mi=0;mi<4;mi++)
      #pragma unroll
      for (int ni=0;ni<4;ni++) acc[mi][ni]=(f32x4){0.f,0.f,0.f,0.f};
    DD_MFMA(acc, Xs, Ps, w, lr, lg);
    {
      float mx = acc[0][0][0];
      #pragma unroll
      for (int mi=0;mi<4;mi++)
        #pragma unroll
        for (int ni=0;ni<4;ni++)
          #pragma unroll
          for (int r=0;r<4;r++) mx=fmaxf(mx,acc[mi][ni][r]);
      #pragma unroll
      for (int m=1;m<64;m<<=1) mx = fmaxf(mx, __shfl_xor(mx,m));
      if (lane==0) rm[w]=mx;
    }
    __syncthreads();                       // Ps reads + Vs transpose done + rm/dgL ready
    {   // vsum partial (4 lanes/row of Vs)
      int d=t>>2, q=t&3;
      float sv=0.f;
      #pragma unroll
      for (int j=0;j<16;j++) sv += b2f(Vs[d*72+q*16+j]);
      sv += __shfl_xor(sv,1); sv += __shfl_xor(sv,2);
      if (q==0) vsacc += sv;
    }
    float dgr[16];                         // preload this thread's diag values
    #pragma unroll
    for (int mi=0;mi<4;mi++)
      #pragma unroll
      for (int r=0;r<4;r++) dgr[mi*4+r] = dgL[mi*16+lg*4+r];
    {
      float tm = SN*fmaxf(fmaxf(rm[0],rm[1]),fmaxf(rm[2],rm[3]));
      float nm = fmaxf(mrun, tm);
      float sc = __expf(mrun - nm);        // 0 on first subtile
      mrun = nm;
      #pragma unroll
      for (int mi=0;mi<4;mi++)
        #pragma unroll
        for (int ni=0;ni<4;ni++)
          #pragma unroll
          for (int r=0;r<4;r++) cacc[mi][ni][r] *= sc;
      #pragma unroll
      for (int ni=0;ni<4;ni++) ksp[ni] *= sc;
    }
    #pragma unroll
    for (int mi=0;mi<4;mi++)
      #pragma unroll
      for (int ni=0;ni<4;ni++){
        int col = w*64+ni*16+lr;
        u16 pk[4];
        #pragma unroll
        for (int r=0;r<4;r++){
          float kp = 0.0625f*__expf(SN*acc[mi][ni][r] - dgr[mi*4+r] - mrun);
          pk[r] = f2b(kp);
          ksp[ni] += kp;
        }
        *(uint2*)&Tr[col*72 + mi*16 + lg*4] = *(uint2*)pk;   // 8B packed write
      }
    __syncthreads();                       // Tr ready
    __builtin_amdgcn_s_setprio(1);
    #pragma unroll
    for (int ks=0;ks<2;ks++){
      bf16x8 aF[4], bF[4];
      #pragma unroll
      for (int mi=0;mi<4;mi++)
        aF[mi]=*(const bf16x8*)(Tr + (w*64+mi*16+lr)*72 + ks*32 + lg*8);
      #pragma unroll
      for (int ni=0;ni<4;ni++)
        bF[ni]=*(const bf16x8*)(Vs + (ni*16+lr)*72 + ks*32 + lg*8);
      #pragma unroll
      for (int mi=0;mi<4;mi++)
        #pragma unroll
        for (int ni=0;ni<4;ni++)
          cacc[mi][ni]=__builtin_amdgcn_mfma_f32_16x16x32_bf16(aF[mi],bF[ni],cacc[mi][ni],0,0,0);
    }
    __builtin_amdgcn_s_setprio(0);
    __syncthreads();                       // before next subtile restage
  }
  #pragma unroll
  for (int ni=0;ni<4;ni++){
    ksp[ni] += __shfl_xor(ksp[ni],16);
    ksp[ni] += __shfl_xor(ksp[ni],32);
  }
  long sb = (long)zl*8+slot;
  if (lane<16){
    float* kb_ = kspart + sb*256;
    #pragma unroll
    for (int ni=0;ni<4;ni++) kb_[w*64+ni*16+lane] = ksp[ni];
  }
  if (t==0) msl[sb]=mrun;
  if ((t&3)==0) vsl[sb*64 + (t>>2)] = vsacc;
  float* pb = part + sb*16384;
  #pragma unroll
  for (int mi=0;mi<4;mi++)
    #pragma unroll
    for (int ni=0;ni<4;ni++){
      int d = ni*16+lr;
      #pragma unroll
      for (int r=0;r<4;r++){
        int m = w*64+mi*16+lg*4+r;
        pb[m*64+d] = cacc[mi][ni][r];
      }
    }
}

// ---- reduce 8 slots w/ global-stab rescale + eps terms ----
// grid (4, CH): q = m-quarter. ksm[z][m] fp32 ; ctxT[z][d][m] bf16.
__global__ __launch_bounds__(256) void ctxred2_k(
    const float* __restrict__ part, const float* __restrict__ kspart,
    const float* __restrict__ msl, const float* __restrict__ vsl,
    u16* __restrict__ ctxT, float* __restrict__ ksm)
{
  int q = blockIdx.x, z = blockIdx.y, t = threadIdx.x;
  const float* pz = part + (long)z*8*16384;
  const float* kz = kspart + (long)z*8*256;
  const float* mz = msl + (long)z*8;
  const float* vz = vsl + (long)z*8*64;
  float mg = mz[0];
  #pragma unroll
  for (int s8=1;s8<8;s8++) mg = fmaxf(mg, mz[s8]);
  float scl[8];
  #pragma unroll
  for (int s8=0;s8<8;s8++) scl[s8] = __expf(mz[s8]-mg);
  __shared__ float vsT[64];
  if (t<64){
    float vv=0.f;
    #pragma unroll
    for (int s8=0;s8<8;s8++) vv += vz[s8*64+t];
    vsT[t]=vv;
  }
  __syncthreads();
  int ml = t&63, dg = t>>6;            // m = q*64+ml, d-range dg*16..+16
  int m  = q*64 + ml;
  f32x4 r4[4];
  #pragma unroll
  for (int j=0;j<4;j++) r4[j]=(f32x4){0.f,0.f,0.f,0.f};
  #pragma unroll
  for (int s8=0;s8<8;s8++){
    const float* ps = pz + (long)s8*16384 + (long)m*64 + dg*16;
    float sc = scl[s8];
    #pragma unroll
    for (int j=0;j<4;j++){
      f32x4 v = *(const f32x4*)(ps + j*4);
      r4[j] += (f32x4){sc*v[0],sc*v[1],sc*v[2],sc*v[3]};
    }
  }
  if (dg==0){
    float s=0.f;
    #pragma unroll
    for (int s8=0;s8<8;s8++) s += kz[s8*256+m]*scl[s8];
    ksm[(long)z*256+m] = s + 0.0128f;      // 0.0625*1e-4*2048
  }
  __shared__ __align__(16) u16 TT[64][72];
  #pragma unroll
  for (int j=0;j<4;j++)
    #pragma unroll
    for (int e=0;e<4;e++){
      int d = dg*16 + j*4 + e;
      TT[d][ml] = f2b(r4[j][e] + 6.25e-6f*vsT[d]);
    }
  __syncthreads();
  int d = t>>2, ms=(t&3)*16;
  union { u16 u[16]; uint4 qq[2]; } tmp;
  #pragma unroll
  for (int j=0;j<16;j++) tmp.u[j]=TT[d][ms+j];
  u16* co = ctxT + (long)z*16384 + d*256 + q*64 + ms;
  *(uint4*)co     = tmp.qq[0];
  *(uint4*)(co+8) = tmp.qq[1];
}

// ---- fused: dd(Q)+diag+rowmax+exp -> qp(LDS) ; dinv in-block ; out = dinv*(qp.ctxT) ----
__global__ __launch_bounds__(256) void ddq_attn_k(
    const u16* __restrict__ Qb, const u16* __restrict__ P,
    const float* __restrict__ ksm, const u16* __restrict__ ctxT,
    u16* __restrict__ at, int zoff)
{
  __shared__ __align__(16) char smem[46336];
  u16*   Ps  = (u16*)smem;
  u16*   qpL = (u16*)smem;                 // [64][264] overlay (33792B)
  float* rdot= (float*)(smem+33792);       // [256]
  float* dnvs= (float*)(smem+34816);       // [64]
  u16*   Xs  = (u16*)(smem+36864);
  float* rm  = (float*)(smem+45056);       // [256]
  float* dgL = (float*)(smem+46080);       // [64]
  int t=threadIdx.x, w=t>>6, lane=t&63, lr=lane&15, lg=lane>>4;
  int zl=blockIdx.y, zg=zl+zoff, n0=blockIdx.x*64;
  int b=zg>>4, hh=zg&15;
  const float SN = 0.35355339059327373f;

  STAGE_PS(Ps, P); STAGE_XS_DG(Xs, Qb, b, hh, n0, dgL);
  __syncthreads();
  f32x4 acc[4][4];
  #pragma unroll
  for (int mi=0;mi<4;mi++)
    #pragma unroll
    for (int ni=0;ni<4;ni++) acc[mi][ni]=(f32x4){0.f,0.f,0.f,0.f};
  DD_MFMA(acc, Xs, Ps, w, lr, lg);
  float rmx[4][4];
  #pragma unroll
  for (int mi=0;mi<4;mi++)
    #pragma unroll
    for (int r=0;r<4;r++){
      float v = acc[mi][0][r];
      #pragma unroll
      for (int ni=1;ni<4;ni++) v=fmaxf(v, acc[mi][ni][r]);
      #pragma unroll
      for (int m=1;m<16;m<<=1) v = fmaxf(v, __shfl_xor(v,m));
      rmx[mi][r]=v;
    }
  if (lr==0){
    #pragma unroll
    for (int mi=0;mi<4;mi++)
      #pragma unroll
      for (int r=0;r<4;r++) rm[w*64 + mi*16 + lg*4 + r] = rmx[mi][r];
  }
  __syncthreads();                         // Ps reads done; rm/dgL ready
  float dgr[16];
  #pragma unroll
  for (int mi=0;mi<4;mi++)
    #pragma unroll
    for (int r=0;r<4;r++) dgr[mi*4+r] = dgL[mi*16+lg*4+r];
  const float* ksz = ksm + (long)zl*256;
  float kcol[4];
  #pragma unroll
  for (int ni=0;ni<4;ni++) kcol[ni] = ksz[w*64+ni*16+lr];
  float rd[4][4];
  #pragma unroll
  for (int mi=0;mi<4;mi++)
    #pragma unroll
    for (int r=0;r<4;r++){
      int rw = mi*16+lg*4+r;
      float st = fmaxf(fmaxf(rm[rw],rm[64+rw]),fmaxf(rm[128+rw],rm[192+rw]));
      float dgv = dgr[mi*4+r];
      float rsum = 0.f;
      #pragma unroll
      for (int ni=0;ni<4;ni++){
        int col = w*64+ni*16+lr;
        float qpv = 0.0625f*(__expf(SN*acc[mi][ni][r] - dgv - SN*st) + 1e-4f);
        qpL[rw*264+col] = f2b(qpv);
        rsum += qpv*kcol[ni];
      }
      rd[mi][r]=rsum;
    }
  #pragma unroll
  for (int mi=0;mi<4;mi++)
    #pragma unroll
    for (int r=0;r<4;r++){
      #pragma unroll
      for (int m=1;m<16;m<<=1) rd[mi][r] += __shfl_xor(rd[mi][r],m);
    }
  if (lr==0){
    #pragma unroll
    for (int mi=0;mi<4;mi++)
      #pragma unroll
      for (int r=0;r<4;r++) rdot[w*64 + mi*16+lg*4+r] = rd[mi][r];
  }
  __syncthreads();
  if (t<64) dnvs[t] = 1.0f/(rdot[t]+rdot[64+t]+rdot[128+t]+rdot[192+t]);
  __syncthreads();
  const u16* cz = ctxT + (long)zl*16384;
  f32x4 aacc[4];
  #pragma unroll
  for (int ni=0;ni<4;ni++) aacc[ni]=(f32x4){0.f,0.f,0.f,0.f};
  __builtin_amdgcn_s_setprio(1);
  #pragma unroll
  for (int ks=0;ks<8;ks++){
    bf16x8 aF = *(const bf16x8*)(qpL + (w*16+lr)*264 + ks*32 + lg*8);
    #pragma unroll
    for (int ni=0;ni<4;ni++){
      bf16x8 bF = *(const bf16x8*)(cz + (ni*16+lr)*256 + ks*32 + lg*8);
      aacc[ni]=__builtin_amdgcn_mfma_f32_16x16x32_bf16(aF,bF,aacc[ni],0,0,0);
    }
  }
  __builtin_amdgcn_s_setprio(0);
  #pragma unroll
  for (int ni=0;ni<4;ni++){
    #pragma unroll
    for (int r=0;r<4;r++){
      int n = n0 + w*16 + lg*4 + r;
      at[((long)b*N_ + n)*D_ + hh*64 + ni*16 + lr] = f2b(aacc[ni][r]*dnvs[w*16+lg*4+r]);
    }
  }
}

// ---------------- 3-buffer counted-vmcnt GEMM: C = A(MxK) * W(NxK)^T ----------
// 512 thr / 8 waves, 4M x 2N wave grid (64x64 wave tiles).
// Period t: vmcnt(6) -> s_barrier -> issue stage(t+2) -> ds_read(t) -> 32 MFMA.
// EPI 1: f32 resid += acc+bias   2: bf16 = gelu(acc+bias)
// EPI 6: fused QKV routed by col>>10, bias from 3 ptrs
template<int EPI,bool XS>
__global__ __launch_bounds__(512,2) void gemm3_k(
    const u16* __restrict__ A, int lda,
    const u16* __restrict__ W, int ldw,
    const float* __restrict__ bias, const float* __restrict__ biasK, const float* __restrict__ biasV,
    void* __restrict__ Cv, int ldc, int K)
{
  constexpr int BM=256, BN=128;
  extern __shared__ __align__(16) u16 lds3[];
  u16* AsB = lds3;                     // 3 * BM*64
  u16* BsB = lds3 + 3*BM*64;           // 3 * BN*64
  int t=threadIdx.x;
  int bx, by;
  if (XS){
    unsigned gx=gridDim.x, flat=blockIdx.y*gx+blockIdx.x;
    unsigned cpx=(gx*gridDim.y)>>3;
    unsigned s=(flat&7)*cpx + (flat>>3);
    bx = s % gx; by = s / gx;
  } else { bx = blockIdx.x; by = blockIdx.y; }
  const u16* Ab = A + (long)by*BM*lda;
  const u16* Wb = W + (long)bx*BN*ldw;
  int w=t>>6, lane=t&63, lr=lane&15, lg=lane>>4;
  int wr=w>>1, wc=w&1;                 // 4 x 2 wave grid; per-wave C = 64 x 64
  int srow=lane>>3, swcol=((lane&7)^srow)*8;   // pre-swizzled global source col
  f32x4 acc[4][4];
  #pragma unroll
  for (int mi=0;mi<4;mi++)
    #pragma unroll
    for (int ni=0;ni<4;ni++) acc[mi][ni]=(f32x4){0.f,0.f,0.f,0.f};

  auto stage=[&](int kt, int sbuf){    // 6 gload16 per thread
    const u16* Ak = Ab + kt*64;
    u16* Ad = AsB + sbuf*(BM*64);
    #pragma unroll
    for (int i=0;i<4;i++){
      int rb=w*32+i*8;
      gload16(Ak + (long)(rb+srow)*lda + swcol, Ad + rb*64);
    }
    const u16* Bk = Wb + kt*64;
    u16* Bd = BsB + sbuf*(BN*64);
    #pragma unroll
    for (int i=0;i<2;i++){
      int rb=w*16+i*8;
      gload16(Bk + (long)(rb+srow)*ldw + swcol, Bd + rb*64);
    }
  };

  const int nK = K/64;
  stage(0,0); if (nK>1) stage(1,1);
  int rbuf=0, sbuf=2;
  for (int kt=0; kt<nK; ++kt){
    if (kt+1<nK) asm volatile("s_waitcnt vmcnt(6)" ::: "memory");
    else         asm volatile("s_waitcnt vmcnt(0)" ::: "memory");
    __builtin_amdgcn_s_barrier();
    if (kt+2<nK) stage(kt+2, sbuf);
    const u16* Al = AsB + rbuf*(BM*64);
    const u16* Bl = BsB + rbuf*(BN*64);
    bf16x8 aF[4][2], bF[4][2];
    #pragma unroll
    for (int ni=0;ni<4;ni++){
      int row=wc*64+ni*16+lr;
      #pragma unroll
      for (int ks=0;ks<2;ks++)
        bF[ni][ks]=*(const bf16x8*)((const char*)Bl + (row<<7) + ((((ks<<2)+lg)<<4)^((row&7)<<4)));
    }
    #pragma unroll
    for (int mi=0;mi<4;mi++){
      int row=wr*64+mi*16+lr;
      #pragma unroll
      for (int ks=0;ks<2;ks++)
        aF[mi][ks]=*(const bf16x8*)((const char*)Al + (row<<7) + ((((ks<<2)+lg)<<4)^((row&7)<<4)));
    }
    #pragma unroll
    for (int ks=0;ks<2;ks++)
      #pragma unroll
      for (int mi=0;mi<4;mi++)
        #pragma unroll
        for (int ni=0;ni<4;ni++)
          acc[mi][ni]=__builtin_amdgcn_mfma_f32_16x16x32_bf16(aF[mi][ks],bF[ni][ks],acc[mi][ni],0,0,0);
    rbuf = (rbuf==2)?0:rbuf+1;
    sbuf = (sbuf==2)?0:sbuf+1;
  }

  #pragma unroll
  for (int mi=0;mi<4;mi++){
    #pragma unroll
    for (int ni=0;ni<4;ni++){
      int col = bx*BN + wc*64 + ni*16 + lr;
      float bv = 0.0f;
      if (EPI==6){
        int seg = col>>10;
        const float* bp = (seg==0)?bias:((seg==1)?biasK:biasV);
        bv = bp[col&1023];
      } else {
        bv = bias[col];
      }
      #pragma unroll
      for (int r=0;r<4;r++){
        int row = by*BM + wr*64 + mi*16 + lg*4 + r;
        float v = acc[mi][ni][r];
        if (EPI==1){
          ((float*)Cv)[(long)row*ldc + col] += v+bv;
        } else if (EPI==2){
          float u=v+bv;
          ((u16*)Cv)[(long)row*ldc + col] = f2b(0.5f*u*(1.0f+erff(u*0.70710678118654752f)));
        } else {
          int seg = col>>10, c = col&1023;
          ((u16*)Cv)[(long)seg*((long)ROWS_*D_) + (long)row*D_ + c] = f2b(v+bv);
        }
      }
    }
  }
}

// =================================================================
struct WS {
  u16 *wbuf, *pjb, *hb, *qb, *kb, *pbuf, *sh16, *ctxT;
  float *part, *kspart, *msl, *vsl, *ksm;
  size_t total;
};
static WS plan_ws(char* base, int allW, int CH){
  WS w; size_t off=0;
  auto al=[&](size_t b)->char*{ char* p=base+off; off=(off+b+255)&~(size_t)255; return p; };
  const size_t TB=(size_t)ROWS_*D_*2;
  w.wbuf=(u16*)al((allW?6ull*L_:6ull)*WN_*2);
  w.pjb =(u16*)al((size_t)L_*M_*DH_*2);
  w.hb  =(u16*)al(TB);
  // qb, kb, pbuf MUST be contiguous (fused-QKV epilogue: seg*ROWS_*D_)
  w.qb  =(u16*)al(TB);
  w.kb  =(u16*)al(TB);
  w.pbuf=(u16*)al(TB);                  // hosts vb (seg 2)
  w.sh16=(u16*)al(TB);                  // FFN intermediate
  w.part=(float*)al((size_t)CH*8*M_*DH_*4);
  w.kspart=(float*)al((size_t)CH*8*M_*4);
  w.msl =(float*)al((size_t)CH*8*4);
  w.vsl =(float*)al((size_t)CH*8*DH_*4);
  w.ctxT=(u16*)al((size_t)BH_*DH_*M_*2);
  w.ksm =(float*)al((size_t)BH_*M_*4);
  w.total=off;
  return w;
}

extern "C" void kernel_launch(void* const* d_in, const int* in_sizes, int n_in,
                              void* d_out, int out_size, void* d_ws, size_t ws_size,
                              hipStream_t stream)
{
  const float* x    = (const float*)d_in[0];
  const float* proj = (const float*)d_in[1];
  const float* ln1g = (const float*)d_in[2];
  const float* ln1b = (const float*)d_in[3];
  const float* Wq   = (const float*)d_in[4];
  const float* bq   = (const float*)d_in[5];
  const float* Wk   = (const float*)d_in[6];
  const float* bk   = (const float*)d_in[7];
  const float* Wv   = (const float*)d_in[8];
  const float* bv   = (const float*)d_in[9];
  const float* Wo   = (const float*)d_in[10];
  const float* bo   = (const float*)d_in[11];
  const float* ln2g = (const float*)d_in[12];
  const float* ln2b = (const float*)d_in[13];
  const float* W1   = (const float*)d_in[14];
  const float* b1   = (const float*)d_in[15];
  const float* W2   = (const float*)d_in[16];
  const float* b2   = (const float*)d_in[17];

  char* base=(char*)d_ws;
  int allW=1, CH=64;
  WS w = plan_ws(base, 1, 64);
  if (w.total > ws_size){ CH=16; w = plan_ws(base, 1, 16); }
  if (w.total > ws_size){ allW=0; w = plan_ws(base, 0, 16); }
  if (w.total > ws_size){
    fillf_k<<<(out_size+255)/256,256,0,stream>>>((float*)d_out,(long)out_size,(float)(ws_size>>20));
    return;
  }
  const int NCH = BH_/CH;

  u16* vb = w.pbuf;     // V output (seg 2 of fused QKV)
  u16* at = w.hb;       // attn out, hb dead between QKV-GEMM and ln2
  u16* tm = w.sh16;     // FFN intermediate

  wcvt_k<<<(L_*M_*DH_/4+255)/256,256,0,stream>>>(proj,w.pjb,(long)L_*M_*DH_);
  if (allW){
    const long na = (long)L_*WN_;
    const int g2 = (int)(na/4/256);
    wcvt2_k<<<g2,256,0,stream>>>(Wq, w.wbuf,         na);
    wcvt2_k<<<g2,256,0,stream>>>(Wk, w.wbuf+WN_,     na);
    wcvt2_k<<<g2,256,0,stream>>>(Wv, w.wbuf+2l*WN_,  na);
    wcvt2_k<<<g2,256,0,stream>>>(Wo, w.wbuf+3l*WN_,  na);
    wcvt2_k<<<g2,256,0,stream>>>(W1, w.wbuf+4l*WN_,  na);
    wcvt2_k<<<g2,256,0,stream>>>(W2, w.wbuf+5l*WN_,  na);
  }
  hipMemcpyAsync(d_out, x, (size_t)ROWS_*D_*4, hipMemcpyDeviceToDevice, stream);
  float* Xc = (float*)d_out;

  const long wn = (long)WN_;
  const int wg = (int)(wn/4/256);
  const size_t G3LDS = 3ull*(256+128)*64*2;   // 147456 B
  dim3 gBig(D_/128, ROWS_/256, 1);       // 8 x 32 = 256 blocks = 1/CU
  dim3 gQKV(3*D_/128, ROWS_/256, 1);     // 24 x 32 = 768 blocks = 3 rounds

  for (int l=0;l<L_;l++){
    u16* lw = w.wbuf + (allW ? (size_t)l*6*wn : 0);
    u16* wqkv=lw;  u16* wo=lw+3*wn;  u16* w1=lw+4*wn;  u16* w2=lw+5*wn;
    if (!allW){
      wcvt_k<<<wg,256,0,stream>>>(Wq+(size_t)l*wn,lw,wn);
      wcvt_k<<<wg,256,0,stream>>>(Wk+(size_t)l*wn,lw+wn,wn);
      wcvt_k<<<wg,256,0,stream>>>(Wv+(size_t)l*wn,lw+2*wn,wn);
      wcvt_k<<<wg,256,0,stream>>>(Wo+(size_t)l*wn,wo,wn);
      wcvt_k<<<wg,256,0,stream>>>(W1+(size_t)l*wn,w1,wn);
      wcvt_k<<<wg,256,0,stream>>>(W2+(size_t)l*wn,w2,wn);
    }
    const u16* pj = w.pjb + (size_t)l*M_*DH_;

    ln_k<<<ROWS_,256,0,stream>>>(Xc, ln1g+(size_t)l*D_, ln1b+(size_t)l*D_, w.hb);
    gemm3_k<6,true><<<gQKV,512,G3LDS,stream>>>(w.hb,D_, wqkv,D_,
        bq+(size_t)l*D_, bk+(size_t)l*D_, bv+(size_t)l*D_, w.qb,D_,D_);

    for (int ch=0; ch<NCH; ch++){
      int zoff = ch*CH;
      ddctx_k<<<dim3(8,CH),256,0,stream>>>(w.kb, pj, vb, w.part, w.kspart,
                                           w.msl, w.vsl, zoff);
      ctxred2_k<<<dim3(4,CH),256,0,stream>>>(w.part, w.kspart, w.msl, w.vsl,
                                     w.ctxT+(long)zoff*DH_*M_, w.ksm+(long)zoff*M_);
      ddq_attn_k<<<dim3(N_/64,CH),256,0,stream>>>(w.qb, pj,
                                                  w.ksm+(long)zoff*M_,
                                                  w.ctxT+(long)zoff*DH_*M_, at, zoff);
    }

    gemm3_k<1,true><<<gBig,512,G3LDS,stream>>>(at,D_, wo,D_,
        bo+(size_t)l*D_, nullptr, nullptr, Xc,D_,D_);
    ln_k<<<ROWS_,256,0,stream>>>(Xc, ln2g+(size_t)l*D_, ln2b+(size_t)l*D_, w.hb);
    gemm3_k<2,true><<<gBig,512,G3LDS,stream>>>(w.hb,D_, w1,D_,
        b1+(size_t)l*D_, nullptr, nullptr, tm,D_,D_);
    gemm3_k<1,true><<<gBig,512,G3LDS,stream>>>(tm,D_, w2,D_,
        b2+(size_t)l*D_, nullptr, nullptr, Xc,D_,D_);
  }
}

// Round 14
// 1148.813 us; speedup vs baseline: 1.0052x; 1.0052x over previous
//
#include <hip/hip_runtime.h>

#define B_    4
#define N_    2048
#define D_    1024
#define L_    4
#define M_    256
#define DH_   64
#define H_    16
#define BH_   64      // B_*H_
#define ROWS_ 8192    // B_*N_
#define WN_   1048576 // D_*D_ = 2^20

typedef __bf16 bf16x8 __attribute__((ext_vector_type(8)));
typedef float  f32x4  __attribute__((ext_vector_type(4)));
typedef unsigned short u16;

__device__ __forceinline__ u16 f2b(float f){
  unsigned u = __float_as_uint(f);
  u += 0x7FFFu + ((u >> 16) & 1u);          // RNE
  return (u16)(u >> 16);
}
__device__ __forceinline__ float b2f(u16 h){ return __uint_as_float(((unsigned)h) << 16); }

// global -> LDS direct, 16B per lane. LDS dest is wave-uniform base + lane*16.
__device__ __forceinline__ void gload16(const u16* g, u16* l){
  __builtin_amdgcn_global_load_lds(
      (const __attribute__((address_space(1))) void*)g,
      (__attribute__((address_space(3))) void*)l, 16, 0, 0);
}

// ---------------- fp32 -> bf16 convert (linear, for proj) ----------------
__global__ __launch_bounds__(256) void wcvt_k(const float* __restrict__ s, u16* __restrict__ d, long n){
  long i = ((long)blockIdx.x*256 + threadIdx.x)*4;
  if (i+3 < n){
    float4 v = *(const float4*)(s+i);
    d[i]=f2b(v.x); d[i+1]=f2b(v.y); d[i+2]=f2b(v.z); d[i+3]=f2b(v.w);
  } else {
    for(long j=i;j<n;j++) d[j]=f2b(s[j]);
  }
}

// ---- merged strided convert: 6 weight tensors in one launch.
// blockIdx.y picks tensor ty; src[l*WN_+j] -> dbase[l*6*WN_ + ty*WN_ + j]
__global__ __launch_bounds__(256) void wcvt6_k(
    const float* __restrict__ s0, const float* __restrict__ s1,
    const float* __restrict__ s2, const float* __restrict__ s3,
    const float* __restrict__ s4, const float* __restrict__ s5,
    u16* __restrict__ dbase)
{
  int ty = blockIdx.y;
  const float* s = (ty==0)?s0:(ty==1)?s1:(ty==2)?s2:(ty==3)?s3:(ty==4)?s4:s5;
  long i = ((long)blockIdx.x*256 + threadIdx.x)*4;
  float4 v = *(const float4*)(s+i);
  long l = i >> 20, j = i & (WN_-1);
  u16* d = dbase + l*(6l*WN_) + (long)ty*WN_ + j;
  d[0]=f2b(v.x); d[1]=f2b(v.y); d[2]=f2b(v.z); d[3]=f2b(v.w);
}

// ---------------- diagnostic fill ----------------
__global__ void fillf_k(float* o, long n, float v){
  long i=(long)blockIdx.x*256+threadIdx.x; if(i<n) o[i]=v;
}

// ---------------- LayerNorm: fp32 row -> bf16 row ----------------
__global__ __launch_bounds__(256) void ln_k(const float* __restrict__ x,
    const float* __restrict__ g, const float* __restrict__ bt, u16* __restrict__ h){
  int row = blockIdx.x, t = threadIdx.x;
  const float* xr = x + (long)row*D_;
  float4 v = *(const float4*)(xr + t*4);
  float s  = v.x+v.y+v.z+v.w;
  float ss = v.x*v.x+v.y*v.y+v.z*v.z+v.w*v.w;
  #pragma unroll
  for (int m=1;m<64;m<<=1){ s += __shfl_xor(s,m); ss += __shfl_xor(ss,m); }
  __shared__ float ps[4][2];
  int w=t>>6;
  if ((t&63)==0){ ps[w][0]=s; ps[w][1]=ss; }
  __syncthreads();
  s  = ps[0][0]+ps[1][0]+ps[2][0]+ps[3][0];
  ss = ps[0][1]+ps[1][1]+ps[2][1]+ps[3][1];
  float mean = s*(1.0f/D_);
  float rs = rsqrtf(ss*(1.0f/D_) - mean*mean + 1e-5f);
  int c=t*4;
  u16* hr = h + (long)row*D_;
  hr[c+0]=f2b((v.x-mean)*rs*g[c+0]+bt[c+0]);
  hr[c+1]=f2b((v.y-mean)*rs*g[c+1]+bt[c+1]);
  hr[c+2]=f2b((v.z-mean)*rs*g[c+2]+bt[c+2]);
  hr[c+3]=f2b((v.w-mean)*rs*g[c+3]+bt[c+3]);
}

// ================= FAVOR fused kernels =================
// proj B-fragments live in REGISTERS (loaded once per block; proj is
// L2-resident 32KB). pF[ni][ks] = proj row (w*64+ni*16+lr), cols ks*32+lg*8.
#define LOAD_PF(pF, P, w, lr, lg) \
  _Pragma("unroll") \
  for (int ni=0;ni<4;ni++) \
    _Pragma("unroll") \
    for (int ks=0;ks<2;ks++) \
      pF[ni][ks] = *(const bf16x8*)((P) + ((w)*64+ni*16+(lr))*64 + ks*32 + (lg)*8);

// staging + in-flight diag: dgL[row] = sum_d x^2 / 16 (8 lanes/row -> 3 shfl)
#define STAGE_XS_DG(Xs, X, b, hh, n0, dgL) \
  _Pragma("unroll") \
  for (int i=0;i<2;i++){ \
    int c=threadIdx.x+i*256, row=c>>3, c8=c&7; \
    uint4 dv = *(const uint4*)((X) + ((long)(b)*N_ + (n0)+row)*D_ + (hh)*DH_ + c8*8); \
    *(uint4*)((char*)(Xs) + (row<<7) + ((c8<<4)^((row&7)<<4))) = dv; \
    const u16* pe=(const u16*)&dv; \
    float sq=0.f; \
    _Pragma("unroll") \
    for (int e=0;e<8;e++){ float xv=b2f(pe[e]); sq += xv*xv; } \
    sq += __shfl_xor(sq,1); sq += __shfl_xor(sq,2); sq += __shfl_xor(sq,4); \
    if ((threadIdx.x&7)==0) (dgL)[row]=sq*0.0625f; \
  }
// dd MFMA: A from swizzled Xs LDS, B from registers
#define DD_MFMA_R(acc, Xs, pF, lr, lg) \
  __builtin_amdgcn_s_setprio(1); \
  _Pragma("unroll") \
  for (int ks=0;ks<2;ks++){ \
    bf16x8 aF[4]; \
    _Pragma("unroll") \
    for (int mi=0;mi<4;mi++){ \
      int row=mi*16+(lr); \
      aF[mi]=*(const bf16x8*)((const char*)(Xs) + (row<<7) + ((((ks<<2)+(lg))<<4)^((row&7)<<4))); \
    } \
    _Pragma("unroll") \
    for (int mi=0;mi<4;mi++) \
      _Pragma("unroll") \
      for (int ni=0;ni<4;ni++) \
        acc[mi][ni]=__builtin_amdgcn_mfma_f32_16x16x32_bf16(aF[mi],pF[ni][ks],acc[mi][ni],0,0,0); \
  } \
  __builtin_amdgcn_s_setprio(0);

// ---- fused: dd(K)+diag+ONLINE-STAB exp -> kp ; ksum/ctx partials ; vsum ----
__global__ __launch_bounds__(256) void ddctx_k(
    const u16* __restrict__ Kb, const u16* __restrict__ P,
    const u16* __restrict__ Vb,
    float* __restrict__ part, float* __restrict__ kspart,
    float* __restrict__ msl, float* __restrict__ vsl, int zoff)
{
  __shared__ __align__(16) char smem[63760];
  u16* Tr = (u16*)smem;               // [0,36864) kp^T (256x72)
  u16* Xs = (u16*)(smem+36864);       // 8KB -> 45056
  u16* Vs = (u16*)(smem+45056);       // [64][72] v^T tile -> 54272
  u16* Tv = (u16*)(smem+54272);       // [64][72] raw V rows -> 63488
  float* dgL = (float*)(smem+63488);  // [64] -> 63744
  float* rm  = (float*)(smem+63744);  // [4]
  int t=threadIdx.x, w=t>>6, lane=t&63, lr=lane&15, lg=lane>>4;
  int zl=blockIdx.y, zg=zl+zoff, slot=blockIdx.x;
  int b=zg>>4, hh=zg&15;
  const float SN = 0.35355339059327373f;

  bf16x8 pF[4][2];
  LOAD_PF(pF, P, w, lr, lg);

  f32x4 cacc[4][4];
  #pragma unroll
  for (int mi=0;mi<4;mi++)
    #pragma unroll
    for (int ni=0;ni<4;ni++) cacc[mi][ni]=(f32x4){0.f,0.f,0.f,0.f};
  float ksp[4]={0.f,0.f,0.f,0.f};
  float vsacc=0.f;                    // valid on (t&3)==0, d=t>>2
  float mrun=-1e30f;

  for (int s=0;s<4;++s){
    int n0 = slot*256 + s*64;
    STAGE_XS_DG(Xs, Kb, b, hh, n0, dgL);
    {   // raw V rows [n][d] into Tv
      int row=t>>2, c16=(t&3)*16;
      const u16* src = Vb + ((long)b*N_ + n0+row)*D_ + hh*DH_ + c16;
      *(uint4*)&Tv[row*72+c16]   = *(const uint4*)src;
      *(uint4*)&Tv[row*72+c16+8] = *(const uint4*)(src+8);
    }
    __syncthreads();
    {   // transpose Tv[n][d] -> Vs[d][n]
      int d=t>>2, nc=(t&3)*16;
      union { u16 u[16]; uint4 q[2]; } tv;
      #pragma unroll
      for (int j=0;j<16;j++) tv.u[j]=Tv[(nc+j)*72+d];
      *(uint4*)&Vs[d*72+nc]   = tv.q[0];
      *(uint4*)&Vs[d*72+nc+8] = tv.q[1];
    }
    f32x4 acc[4][4];
    #pragma unroll
    for (int mi=0;mi<4;mi++)
      #pragma unroll
      for (int ni=0;ni<4;ni++) acc[mi][ni]=(f32x4){0.f,0.f,0.f,0.f};
    DD_MFMA_R(acc, Xs, pF, lr, lg);
    {
      float mx = acc[0][0][0];
      #pragma unroll
      for (int mi=0;mi<4;mi++)
        #pragma unroll
        for (int ni=0;ni<4;ni++)
          #pragma unroll
          for (int r=0;r<4;r++) mx=fmaxf(mx,acc[mi][ni][r]);
      #pragma unroll
      for (int m=1;m<64;m<<=1) mx = fmaxf(mx, __shfl_xor(mx,m));
      if (lane==0) rm[w]=mx;
    }
    __syncthreads();                       // Vs transpose done + rm/dgL ready
    {   // vsum partial (4 lanes/row of Vs)
      int d=t>>2, q=t&3;
      float sv=0.f;
      #pragma unroll
      for (int j=0;j<16;j++) sv += b2f(Vs[d*72+q*16+j]);
      sv += __shfl_xor(sv,1); sv += __shfl_xor(sv,2);
      if (q==0) vsacc += sv;
    }
    float dgr[16];                         // preload this thread's diag values
    #pragma unroll
    for (int mi=0;mi<4;mi++)
      #pragma unroll
      for (int r=0;r<4;r++) dgr[mi*4+r] = dgL[mi*16+lg*4+r];
    {
      float tm = SN*fmaxf(fmaxf(rm[0],rm[1]),fmaxf(rm[2],rm[3]));
      float nm = fmaxf(mrun, tm);
      float sc = __expf(mrun - nm);        // 0 on first subtile
      mrun = nm;
      #pragma unroll
      for (int mi=0;mi<4;mi++)
        #pragma unroll
        for (int ni=0;ni<4;ni++)
          #pragma unroll
          for (int r=0;r<4;r++) cacc[mi][ni][r] *= sc;
      #pragma unroll
      for (int ni=0;ni<4;ni++) ksp[ni] *= sc;
    }
    #pragma unroll
    for (int mi=0;mi<4;mi++)
      #pragma unroll
      for (int ni=0;ni<4;ni++){
        int col = w*64+ni*16+lr;
        u16 pk[4];
        #pragma unroll
        for (int r=0;r<4;r++){
          float kp = 0.0625f*__expf(SN*acc[mi][ni][r] - dgr[mi*4+r] - mrun);
          pk[r] = f2b(kp);
          ksp[ni] += kp;
        }
        *(uint2*)&Tr[col*72 + mi*16 + lg*4] = *(uint2*)pk;   // 8B packed write
      }
    __syncthreads();                       // Tr ready
    __builtin_amdgcn_s_setprio(1);
    #pragma unroll
    for (int ks=0;ks<2;ks++){
      bf16x8 aF[4], bF[4];
      #pragma unroll
      for (int mi=0;mi<4;mi++)
        aF[mi]=*(const bf16x8*)(Tr + (w*64+mi*16+lr)*72 + ks*32 + lg*8);
      #pragma unroll
      for (int ni=0;ni<4;ni++)
        bF[ni]=*(const bf16x8*)(Vs + (ni*16+lr)*72 + ks*32 + lg*8);
      #pragma unroll
      for (int mi=0;mi<4;mi++)
        #pragma unroll
        for (int ni=0;ni<4;ni++)
          cacc[mi][ni]=__builtin_amdgcn_mfma_f32_16x16x32_bf16(aF[mi],bF[ni],cacc[mi][ni],0,0,0);
    }
    __builtin_amdgcn_s_setprio(0);
    __syncthreads();                       // before next subtile restage
  }
  #pragma unroll
  for (int ni=0;ni<4;ni++){
    ksp[ni] += __shfl_xor(ksp[ni],16);
    ksp[ni] += __shfl_xor(ksp[ni],32);
  }
  long sb = (long)zl*8+slot;
  if (lane<16){
    float* kb_ = kspart + sb*256;
    #pragma unroll
    for (int ni=0;ni<4;ni++) kb_[w*64+ni*16+lane] = ksp[ni];
  }
  if (t==0) msl[sb]=mrun;
  if ((t&3)==0) vsl[sb*64 + (t>>2)] = vsacc;
  float* pb = part + sb*16384;
  #pragma unroll
  for (int mi=0;mi<4;mi++)
    #pragma unroll
    for (int ni=0;ni<4;ni++){
      int d = ni*16+lr;
      #pragma unroll
      for (int r=0;r<4;r++){
        int m = w*64+mi*16+lg*4+r;
        pb[m*64+d] = cacc[mi][ni][r];
      }
    }
}

// ---- reduce 8 slots w/ global-stab rescale + eps terms ----
// grid (4, CH): q = m-quarter. ksm[z][m] fp32 ; ctxT[z][d][m] bf16.
__global__ __launch_bounds__(256) void ctxred2_k(
    const float* __restrict__ part, const float* __restrict__ kspart,
    const float* __restrict__ msl, const float* __restrict__ vsl,
    u16* __restrict__ ctxT, float* __restrict__ ksm)
{
  int q = blockIdx.x, z = blockIdx.y, t = threadIdx.x;
  const float* pz = part + (long)z*8*16384;
  const float* kz = kspart + (long)z*8*256;
  const float* mz = msl + (long)z*8;
  const float* vz = vsl + (long)z*8*64;
  float mg = mz[0];
  #pragma unroll
  for (int s8=1;s8<8;s8++) mg = fmaxf(mg, mz[s8]);
  float scl[8];
  #pragma unroll
  for (int s8=0;s8<8;s8++) scl[s8] = __expf(mz[s8]-mg);
  __shared__ float vsT[64];
  if (t<64){
    float vv=0.f;
    #pragma unroll
    for (int s8=0;s8<8;s8++) vv += vz[s8*64+t];
    vsT[t]=vv;
  }
  __syncthreads();
  int ml = t&63, dg = t>>6;            // m = q*64+ml, d-range dg*16..+16
  int m  = q*64 + ml;
  f32x4 r4[4];
  #pragma unroll
  for (int j=0;j<4;j++) r4[j]=(f32x4){0.f,0.f,0.f,0.f};
  #pragma unroll
  for (int s8=0;s8<8;s8++){
    const float* ps = pz + (long)s8*16384 + (long)m*64 + dg*16;
    float sc = scl[s8];
    #pragma unroll
    for (int j=0;j<4;j++){
      f32x4 v = *(const f32x4*)(ps + j*4);
      r4[j] += (f32x4){sc*v[0],sc*v[1],sc*v[2],sc*v[3]};
    }
  }
  if (dg==0){
    float s=0.f;
    #pragma unroll
    for (int s8=0;s8<8;s8++) s += kz[s8*256+m]*scl[s8];
    ksm[(long)z*256+m] = s + 0.0128f;      // 0.0625*1e-4*2048
  }
  __shared__ __align__(16) u16 TT[64][72];
  #pragma unroll
  for (int j=0;j<4;j++)
    #pragma unroll
    for (int e=0;e<4;e++){
      int d = dg*16 + j*4 + e;
      TT[d][ml] = f2b(r4[j][e] + 6.25e-6f*vsT[d]);
    }
  __syncthreads();
  int d = t>>2, ms=(t&3)*16;
  union { u16 u[16]; uint4 qq[2]; } tmp;
  #pragma unroll
  for (int j=0;j<16;j++) tmp.u[j]=TT[d][ms+j];
  u16* co = ctxT + (long)z*16384 + d*256 + q*64 + ms;
  *(uint4*)co     = tmp.qq[0];
  *(uint4*)(co+8) = tmp.qq[1];
}

// ---- fused: dd(Q)+diag+rowmax+exp -> qp(LDS) ; dinv in-block ; out = dinv*(qp.ctxT) ----
__global__ __launch_bounds__(256) void ddq_attn_k(
    const u16* __restrict__ Qb, const u16* __restrict__ P,
    const float* __restrict__ ksm, const u16* __restrict__ ctxT,
    u16* __restrict__ at, int zoff)
{
  __shared__ __align__(16) char smem[46336];
  u16*   qpL = (u16*)smem;                 // [64][264] (33792B)
  float* rdot= (float*)(smem+33792);       // [256]
  float* dnvs= (float*)(smem+34816);       // [64]
  u16*   Xs  = (u16*)(smem+36864);
  float* rm  = (float*)(smem+45056);       // [256]
  float* dgL = (float*)(smem+46080);       // [64]
  int t=threadIdx.x, w=t>>6, lane=t&63, lr=lane&15, lg=lane>>4;
  int zl=blockIdx.y, zg=zl+zoff, n0=blockIdx.x*64;
  int b=zg>>4, hh=zg&15;
  const float SN = 0.35355339059327373f;

  bf16x8 pF[4][2];
  LOAD_PF(pF, P, w, lr, lg);
  STAGE_XS_DG(Xs, Qb, b, hh, n0, dgL);
  __syncthreads();
  f32x4 acc[4][4];
  #pragma unroll
  for (int mi=0;mi<4;mi++)
    #pragma unroll
    for (int ni=0;ni<4;ni++) acc[mi][ni]=(f32x4){0.f,0.f,0.f,0.f};
  DD_MFMA_R(acc, Xs, pF, lr, lg);
  float rmx[4][4];
  #pragma unroll
  for (int mi=0;mi<4;mi++)
    #pragma unroll
    for (int r=0;r<4;r++){
      float v = acc[mi][0][r];
      #pragma unroll
      for (int ni=1;ni<4;ni++) v=fmaxf(v, acc[mi][ni][r]);
      #pragma unroll
      for (int m=1;m<16;m<<=1) v = fmaxf(v, __shfl_xor(v,m));
      rmx[mi][r]=v;
    }
  if (lr==0){
    #pragma unroll
    for (int mi=0;mi<4;mi++)
      #pragma unroll
      for (int r=0;r<4;r++) rm[w*64 + mi*16 + lg*4 + r] = rmx[mi][r];
  }
  __syncthreads();                         // rm/dgL ready
  float dgr[16];
  #pragma unroll
  for (int mi=0;mi<4;mi++)
    #pragma unroll
    for (int r=0;r<4;r++) dgr[mi*4+r] = dgL[mi*16+lg*4+r];
  const float* ksz = ksm + (long)zl*256;
  float kcol[4];
  #pragma unroll
  for (int ni=0;ni<4;ni++) kcol[ni] = ksz[w*64+ni*16+lr];
  float rd[4][4];
  #pragma unroll
  for (int mi=0;mi<4;mi++)
    #pragma unroll
    for (int r=0;r<4;r++){
      int rw = mi*16+lg*4+r;
      float st = fmaxf(fmaxf(rm[rw],rm[64+rw]),fmaxf(rm[128+rw],rm[192+rw]));
      float dgv = dgr[mi*4+r];
      float rsum = 0.f;
      #pragma unroll
      for (int ni=0;ni<4;ni++){
        int col = w*64+ni*16+lr;
        float qpv = 0.0625f*(__expf(SN*acc[mi][ni][r] - dgv - SN*st) + 1e-4f);
        qpL[rw*264+col] = f2b(qpv);
        rsum += qpv*kcol[ni];
      }
      rd[mi][r]=rsum;
    }
  #pragma unroll
  for (int mi=0;mi<4;mi++)
    #pragma unroll
    for (int r=0;r<4;r++){
      #pragma unroll
      for (int m=1;m<16;m<<=1) rd[mi][r] += __shfl_xor(rd[mi][r],m);
    }
  if (lr==0){
    #pragma unroll
    for (int mi=0;mi<4;mi++)
      #pragma unroll
      for (int r=0;r<4;r++) rdot[w*64 + mi*16+lg*4+r] = rd[mi][r];
  }
  __syncthreads();
  if (t<64) dnvs[t] = 1.0f/(rdot[t]+rdot[64+t]+rdot[128+t]+rdot[192+t]);
  __syncthreads();
  const u16* cz = ctxT + (long)zl*16384;
  f32x4 aacc[4];
  #pragma unroll
  for (int ni=0;ni<4;ni++) aacc[ni]=(f32x4){0.f,0.f,0.f,0.f};
  __builtin_amdgcn_s_setprio(1);
  #pragma unroll
  for (int ks=0;ks<8;ks++){
    bf16x8 aF = *(const bf16x8*)(qpL + (w*16+lr)*264 + ks*32 + lg*8);
    #pragma unroll
    for (int ni=0;ni<4;ni++){
      bf16x8 bF = *(const bf16x8*)(cz + (ni*16+lr)*256 + ks*32 + lg*8);
      aacc[ni]=__builtin_amdgcn_mfma_f32_16x16x32_bf16(aF,bF,aacc[ni],0,0,0);
    }
  }
  __builtin_amdgcn_s_setprio(0);
  #pragma unroll
  for (int ni=0;ni<4;ni++){
    #pragma unroll
    for (int r=0;r<4;r++){
      int n = n0 + w*16 + lg*4 + r;
      at[((long)b*N_ + n)*D_ + hh*64 + ni*16 + lr] = f2b(aacc[ni][r]*dnvs[w*16+lg*4+r]);
    }
  }
}

// ---------------- 3-buffer counted-vmcnt GEMM: C = A(MxK) * W(NxK)^T ----------
// 512 thr / 8 waves, 4M x 2N wave grid (64x64 wave tiles).
// Period t: vmcnt(6) -> s_barrier -> issue stage(t+2) -> ds_read(t) -> 32 MFMA.
// EPI 1: f32 resid += acc+bias   2: bf16 = gelu(acc+bias)
// EPI 6: fused QKV routed by col>>10, bias from 3 ptrs
template<int EPI,bool XS>
__global__ __launch_bounds__(512,2) void gemm3_k(
    const u16* __restrict__ A, int lda,
    const u16* __restrict__ W, int ldw,
    const float* __restrict__ bias, const float* __restrict__ biasK, const float* __restrict__ biasV,
    void* __restrict__ Cv, int ldc, int K)
{
  constexpr int BM=256, BN=128;
  extern __shared__ __align__(16) u16 lds3[];
  u16* AsB = lds3;                     // 3 * BM*64
  u16* BsB = lds3 + 3*BM*64;           // 3 * BN*64
  int t=threadIdx.x;
  int bx, by;
  if (XS){
    unsigned gx=gridDim.x, flat=blockIdx.y*gx+blockIdx.x;
    unsigned cpx=(gx*gridDim.y)>>3;
    unsigned s=(flat&7)*cpx + (flat>>3);
    bx = s % gx; by = s / gx;
  } else { bx = blockIdx.x; by = blockIdx.y; }
  const u16* Ab = A + (long)by*BM*lda;
  const u16* Wb = W + (long)bx*BN*ldw;
  int w=t>>6, lane=t&63, lr=lane&15, lg=lane>>4;
  int wr=w>>1, wc=w&1;                 // 4 x 2 wave grid; per-wave C = 64 x 64
  int srow=lane>>3, swcol=((lane&7)^srow)*8;   // pre-swizzled global source col
  f32x4 acc[4][4];
  #pragma unroll
  for (int mi=0;mi<4;mi++)
    #pragma unroll
    for (int ni=0;ni<4;ni++) acc[mi][ni]=(f32x4){0.f,0.f,0.f,0.f};

  auto stage=[&](int kt, int sbuf){    // 6 gload16 per thread
    const u16* Ak = Ab + kt*64;
    u16* Ad = AsB + sbuf*(BM*64);
    #pragma unroll
    for (int i=0;i<4;i++){
      int rb=w*32+i*8;
      gload16(Ak + (long)(rb+srow)*lda + swcol, Ad + rb*64);
    }
    const u16* Bk = Wb + kt*64;
    u16* Bd = BsB + sbuf*(BN*64);
    #pragma unroll
    for (int i=0;i<2;i++){
      int rb=w*16+i*8;
      gload16(Bk + (long)(rb+srow)*ldw + swcol, Bd + rb*64);
    }
  };

  const int nK = K/64;
  stage(0,0); if (nK>1) stage(1,1);
  int rbuf=0, sbuf=2;
  for (int kt=0; kt<nK; ++kt){
    if (kt+1<nK) asm volatile("s_waitcnt vmcnt(6)" ::: "memory");
    else         asm volatile("s_waitcnt vmcnt(0)" ::: "memory");
    __builtin_amdgcn_s_barrier();
    if (kt+2<nK) stage(kt+2, sbuf);
    const u16* Al = AsB + rbuf*(BM*64);
    const u16* Bl = BsB + rbuf*(BN*64);
    bf16x8 aF[4][2], bF[4][2];
    #pragma unroll
    for (int ni=0;ni<4;ni++){
      int row=wc*64+ni*16+lr;
      #pragma unroll
      for (int ks=0;ks<2;ks++)
        bF[ni][ks]=*(const bf16x8*)((const char*)Bl + (row<<7) + ((((ks<<2)+lg)<<4)^((row&7)<<4)));
    }
    #pragma unroll
    for (int mi=0;mi<4;mi++){
      int row=wr*64+mi*16+lr;
      #pragma unroll
      for (int ks=0;ks<2;ks++)
        aF[mi][ks]=*(const bf16x8*)((const char*)Al + (row<<7) + ((((ks<<2)+lg)<<4)^((row&7)<<4)));
    }
    #pragma unroll
    for (int ks=0;ks<2;ks++)
      #pragma unroll
      for (int mi=0;mi<4;mi++)
        #pragma unroll
        for (int ni=0;ni<4;ni++)
          acc[mi][ni]=__builtin_amdgcn_mfma_f32_16x16x32_bf16(aF[mi][ks],bF[ni][ks],acc[mi][ni],0,0,0);
    rbuf = (rbuf==2)?0:rbuf+1;
    sbuf = (sbuf==2)?0:sbuf+1;
  }

  #pragma unroll
  for (int mi=0;mi<4;mi++){
    #pragma unroll
    for (int ni=0;ni<4;ni++){
      int col = bx*BN + wc*64 + ni*16 + lr;
      float bv = 0.0f;
      if (EPI==6){
        int seg = col>>10;
        const float* bp = (seg==0)?bias:((seg==1)?biasK:biasV);
        bv = bp[col&1023];
      } else {
        bv = bias[col];
      }
      #pragma unroll
      for (int r=0;r<4;r++){
        int row = by*BM + wr*64 + mi*16 + lg*4 + r;
        float v = acc[mi][ni][r];
        if (EPI==1){
          ((float*)Cv)[(long)row*ldc + col] += v+bv;
        } else if (EPI==2){
          float u=v+bv;
          ((u16*)Cv)[(long)row*ldc + col] = f2b(0.5f*u*(1.0f+erff(u*0.70710678118654752f)));
        } else {
          int seg = col>>10, c = col&1023;
          ((u16*)Cv)[(long)seg*((long)ROWS_*D_) + (long)row*D_ + c] = f2b(v+bv);
        }
      }
    }
  }
}

// =================================================================
struct WS {
  u16 *wbuf, *pjb, *hb, *qb, *kb, *pbuf, *sh16, *ctxT;
  float *part, *kspart, *msl, *vsl, *ksm;
  size_t total;
};
static WS plan_ws(char* base, int allW, int CH){
  WS w; size_t off=0;
  auto al=[&](size_t b)->char*{ char* p=base+off; off=(off+b+255)&~(size_t)255; return p; };
  const size_t TB=(size_t)ROWS_*D_*2;
  w.wbuf=(u16*)al((allW?6ull*L_:6ull)*WN_*2);
  w.pjb =(u16*)al((size_t)L_*M_*DH_*2);
  w.hb  =(u16*)al(TB);
  // qb, kb, pbuf MUST be contiguous (fused-QKV epilogue: seg*ROWS_*D_)
  w.qb  =(u16*)al(TB);
  w.kb  =(u16*)al(TB);
  w.pbuf=(u16*)al(TB);                  // hosts vb (seg 2)
  w.sh16=(u16*)al(TB);                  // FFN intermediate
  w.part=(float*)al((size_t)CH*8*M_*DH_*4);
  w.kspart=(float*)al((size_t)CH*8*M_*4);
  w.msl =(float*)al((size_t)CH*8*4);
  w.vsl =(float*)al((size_t)CH*8*DH_*4);
  w.ctxT=(u16*)al((size_t)BH_*DH_*M_*2);
  w.ksm =(float*)al((size_t)BH_*M_*4);
  w.total=off;
  return w;
}

extern "C" void kernel_launch(void* const* d_in, const int* in_sizes, int n_in,
                              void* d_out, int out_size, void* d_ws, size_t ws_size,
                              hipStream_t stream)
{
  const float* x    = (const float*)d_in[0];
  const float* proj = (const float*)d_in[1];
  const float* ln1g = (const float*)d_in[2];
  const float* ln1b = (const float*)d_in[3];
  const float* Wq   = (const float*)d_in[4];
  const float* bq   = (const float*)d_in[5];
  const float* Wk   = (const float*)d_in[6];
  const float* bk   = (const float*)d_in[7];
  const float* Wv   = (const float*)d_in[8];
  const float* bv   = (const float*)d_in[9];
  const float* Wo   = (const float*)d_in[10];
  const float* bo   = (const float*)d_in[11];
  const float* ln2g = (const float*)d_in[12];
  const float* ln2b = (const float*)d_in[13];
  const float* W1   = (const float*)d_in[14];
  const float* b1   = (const float*)d_in[15];
  const float* W2   = (const float*)d_in[16];
  const float* b2   = (const float*)d_in[17];

  char* base=(char*)d_ws;
  int allW=1, CH=64;
  WS w = plan_ws(base, 1, 64);
  if (w.total > ws_size){ CH=16; w = plan_ws(base, 1, 16); }
  if (w.total > ws_size){ allW=0; w = plan_ws(base, 0, 16); }
  if (w.total > ws_size){
    fillf_k<<<(out_size+255)/256,256,0,stream>>>((float*)d_out,(long)out_size,(float)(ws_size>>20));
    return;
  }
  const int NCH = BH_/CH;

  u16* vb = w.pbuf;     // V output (seg 2 of fused QKV)
  u16* at = w.hb;       // attn out, hb dead between QKV-GEMM and ln2
  u16* tm = w.sh16;     // FFN intermediate

  wcvt_k<<<(L_*M_*DH_/4+255)/256,256,0,stream>>>(proj,w.pjb,(long)L_*M_*DH_);
  if (allW){
    const long na = (long)L_*WN_;
    const int g2 = (int)(na/4/256);
    wcvt6_k<<<dim3(g2,6),256,0,stream>>>(Wq,Wk,Wv,Wo,W1,W2, w.wbuf);
  }
  hipMemcpyAsync(d_out, x, (size_t)ROWS_*D_*4, hipMemcpyDeviceToDevice, stream);
  float* Xc = (float*)d_out;

  const long wn = (long)WN_;
  const int wg = (int)(wn/4/256);
  const size_t G3LDS = 3ull*(256+128)*64*2;   // 147456 B
  dim3 gBig(D_/128, ROWS_/256, 1);       // 8 x 32 = 256 blocks = 1/CU
  dim3 gQKV(3*D_/128, ROWS_/256, 1);     // 24 x 32 = 768 blocks = 3 rounds

  for (int l=0;l<L_;l++){
    u16* lw = w.wbuf + (allW ? (size_t)l*6*wn : 0);
    u16* wqkv=lw;  u16* wo=lw+3*wn;  u16* w1=lw+4*wn;  u16* w2=lw+5*wn;
    if (!allW){
      wcvt_k<<<wg,256,0,stream>>>(Wq+(size_t)l*wn,lw,wn);
      wcvt_k<<<wg,256,0,stream>>>(Wk+(size_t)l*wn,lw+wn,wn);
      wcvt_k<<<wg,256,0,stream>>>(Wv+(size_t)l*wn,lw+2*wn,wn);
      wcvt_k<<<wg,256,0,stream>>>(Wo+(size_t)l*wn,wo,wn);
      wcvt_k<<<wg,256,0,stream>>>(W1+(size_t)l*wn,w1,wn);
      wcvt_k<<<wg,256,0,stream>>>(W2+(size_t)l*wn,w2,wn);
    }
    const u16* pj = w.pjb + (size_t)l*M_*DH_;

    ln_k<<<ROWS_,256,0,stream>>>(Xc, ln1g+(size_t)l*D_, ln1b+(size_t)l*D_, w.hb);
    gemm3_k<6,true><<<gQKV,512,G3LDS,stream>>>(w.hb,D_, wqkv,D_,
        bq+(size_t)l*D_, bk+(size_t)l*D_, bv+(size_t)l*D_, w.qb,D_,D_);

    for (int ch=0; ch<NCH; ch++){
      int zoff = ch*CH;
      ddctx_k<<<dim3(8,CH),256,0,stream>>>(w.kb, pj, vb, w.part, w.kspart,
                                           w.msl, w.vsl, zoff);
      ctxred2_k<<<dim3(4,CH),256,0,stream>>>(w.part, w.kspart, w.msl, w.vsl,
                                     w.ctxT+(long)zoff*DH_*M_, w.ksm+(long)zoff*M_);
      ddq_attn_k<<<dim3(N_/64,CH),256,0,stream>>>(w.qb, pj,
                                                  w.ksm+(long)zoff*M_,
                                                  w.ctxT+(long)zoff*DH_*M_, at, zoff);
    }

    gemm3_k<1,true><<<gBig,512,G3LDS,stream>>>(at,D_, wo,D_,
        bo+(size_t)l*D_, nullptr, nullptr, Xc,D_,D_);
    ln_k<<<ROWS_,256,0,stream>>>(Xc, ln2g+(size_t)l*D_, ln2b+(size_t)l*D_, w.hb);
    gemm3_k<2,true><<<gBig,512,G3LDS,stream>>>(w.hb,D_, w1,D_,
        b1+(size_t)l*D_, nullptr, nullptr, tm,D_,D_);
    gemm3_k<1,true><<<gBig,512,G3LDS,stream>>>(tm,D_, w2,D_,
        b2+(size_t)l*D_, nullptr, nullptr, Xc,D_,D_);
  }
}